// Round 1
// baseline (264.304 us; speedup 1.0000x reference)
//
#include <hip/hip_runtime.h>
#include <hip/hip_bf16.h>
#include <math.h>

// Problem constants (from reference): B=4, T=8192, D=512, S=16
#define B_ 4
#define T_ 8192
#define D_ 512
#define S_ 16

// ---------------------------------------------------------------------------
// Kernel 1: attn[b,t,s] = softmax_s( -0.5*||x[b,t]-c[s]||^2 / scale[s]^2 )
// One wave (64 lanes) per token. Centers held in registers, stride-64 layout:
// lane L holds centers[s][64*j + L] for j=0..7. 17-value butterfly reduce.
// ---------------------------------------------------------------------------
__global__ __launch_bounds__(256) void attn_k(const float* __restrict__ x,
                                              const float* __restrict__ centers,
                                              const float* __restrict__ log_scales,
                                              float* __restrict__ attn) {
  const int lane = threadIdx.x & 63;
  const int wid = (blockIdx.x << 2) + (threadIdx.x >> 6);
  const int nw = gridDim.x << 2;

  // centers in registers: 16 splats x 8 elems/lane = 128 VGPRs
  float c_reg[S_][8];
#pragma unroll
  for (int s = 0; s < S_; ++s)
#pragma unroll
    for (int j = 0; j < 8; ++j)
      c_reg[s][j] = centers[s * D_ + (j << 6) + lane];

  // per-lane (lane==s) c2 and 0.5/scale^2
  float c2l = 0.f, inv2l = 0.f;
  {
    float part[S_];
#pragma unroll
    for (int s = 0; s < S_; ++s) {
      float a = 0.f;
#pragma unroll
      for (int j = 0; j < 8; ++j) a += c_reg[s][j] * c_reg[s][j];
      part[s] = a;
    }
#pragma unroll
    for (int off = 32; off >= 1; off >>= 1)
#pragma unroll
      for (int s = 0; s < S_; ++s) part[s] += __shfl_xor(part[s], off, 64);
    if (lane < S_) {
      c2l = part[lane];
      float sc = fminf(fmaxf(__expf(log_scales[lane]), 0.1f), 2.0f);
      inv2l = 0.5f / (sc * sc);
    }
  }

  const int total = B_ * T_;
  for (int t = wid; t < total; t += nw) {
    const float* xr = x + (size_t)t * D_;
    float xv[8];
#pragma unroll
    for (int j = 0; j < 8; ++j) xv[j] = xr[(j << 6) + lane];

    float x2 = 0.f;
#pragma unroll
    for (int j = 0; j < 8; ++j) x2 += xv[j] * xv[j];

    float acc[S_];
#pragma unroll
    for (int s = 0; s < S_; ++s) {
      float a = 0.f;
#pragma unroll
      for (int j = 0; j < 8; ++j) a += xv[j] * c_reg[s][j];
      acc[s] = a;
    }

    // butterfly reduce x2 + 16 dots across the wave (result in all lanes)
#pragma unroll
    for (int off = 32; off >= 1; off >>= 1) {
      x2 += __shfl_xor(x2, off, 64);
#pragma unroll
      for (int s = 0; s < S_; ++s) acc[s] += __shfl_xor(acc[s], off, 64);
    }

    // lane s (s<16) owns logit[s]; softmax across lanes 0..15 (others -> 0)
    float logit = -3.0e38f;
    if (lane < S_) logit = -(x2 - 2.f * acc[lane] + c2l) * inv2l;
    float m = logit;
#pragma unroll
    for (int off = 32; off >= 1; off >>= 1) m = fmaxf(m, __shfl_xor(m, off, 64));
    float e = __expf(logit - m);  // lanes >= 16: exp(-huge) == 0
    float ssum = e;
#pragma unroll
    for (int off = 32; off >= 1; off >>= 1) ssum += __shfl_xor(ssum, off, 64);
    if (lane < S_) attn[(size_t)t * S_ + lane] = e / ssum;
  }
}

// ---------------------------------------------------------------------------
// Kernel 2: ts[b,s,d] = sum_t attn[b,t,s] * x[b,t,d]  (split-K over tokens,
// thread-per-d-column, attn chunk in LDS, fp32 atomics for the K-reduction)
// ---------------------------------------------------------------------------
#define K2_TOK 128
__global__ __launch_bounds__(512) void ts_k(const float* __restrict__ x,
                                            const float* __restrict__ attn,
                                            float* __restrict__ ts) {
  __shared__ __align__(16) float a_s[K2_TOK * S_];  // 8 KB
  const int chunks = T_ / K2_TOK;
  const int b = blockIdx.x / chunks;
  const int t0 = (blockIdx.x % chunks) * K2_TOK;

  const float* ab = attn + ((size_t)b * T_ + t0) * S_;
  for (int i = threadIdx.x; i < K2_TOK * S_; i += 512) a_s[i] = ab[i];
  __syncthreads();

  const int d = threadIdx.x;  // 0..511 == D_
  float acc[S_];
#pragma unroll
  for (int s = 0; s < S_; ++s) acc[s] = 0.f;

  const float* xb = x + ((size_t)b * T_ + t0) * D_ + d;
  for (int t = 0; t < K2_TOK; ++t) {
    float xv = xb[(size_t)t * D_];
    const float4* ap = (const float4*)(a_s + t * S_);  // broadcast reads
    float4 a0 = ap[0], a1 = ap[1], a2 = ap[2], a3 = ap[3];
    acc[0]  += a0.x * xv; acc[1]  += a0.y * xv; acc[2]  += a0.z * xv; acc[3]  += a0.w * xv;
    acc[4]  += a1.x * xv; acc[5]  += a1.y * xv; acc[6]  += a1.z * xv; acc[7]  += a1.w * xv;
    acc[8]  += a2.x * xv; acc[9]  += a2.y * xv; acc[10] += a2.z * xv; acc[11] += a2.w * xv;
    acc[12] += a3.x * xv; acc[13] += a3.y * xv; acc[14] += a3.z * xv; acc[15] += a3.w * xv;
  }

  float* tb = ts + (size_t)b * S_ * D_ + d;
#pragma unroll
  for (int s = 0; s < S_; ++s) atomicAdd(tb + s * D_, acc[s]);
}

// ---------------------------------------------------------------------------
// Kernel 3: ss_o[b,s,:] = (ts[b,s,:] @ Wv^T) @ Wo^T   (two tiny GEMMs)
// One block per (b,s) row; both stages through LDS.
// ---------------------------------------------------------------------------
__global__ __launch_bounds__(256) void ssgemm_k(const float* __restrict__ ts,
                                                const float* __restrict__ Wv,
                                                const float* __restrict__ Wo,
                                                float* __restrict__ ss_o) {
  __shared__ __align__(16) float row[D_];
  __shared__ __align__(16) float tmp[D_];

  const float* tr = ts + (size_t)blockIdx.x * D_;
  for (int i = threadIdx.x; i < D_; i += 256) row[i] = tr[i];
  __syncthreads();

  for (int e = threadIdx.x; e < D_; e += 256) {
    const float4* w = (const float4*)(Wv + (size_t)e * D_);
    const float4* r = (const float4*)row;
    float acc = 0.f;
#pragma unroll 4
    for (int k = 0; k < D_ / 4; ++k) {
      float4 wv = w[k], rv = r[k];
      acc += wv.x * rv.x + wv.y * rv.y + wv.z * rv.z + wv.w * rv.w;
    }
    tmp[e] = acc;
  }
  __syncthreads();

  float* ob = ss_o + (size_t)blockIdx.x * D_;
  for (int e = threadIdx.x; e < D_; e += 256) {
    const float4* w = (const float4*)(Wo + (size_t)e * D_);
    const float4* r = (const float4*)tmp;
    float acc = 0.f;
#pragma unroll 4
    for (int k = 0; k < D_ / 4; ++k) {
      float4 wv = w[k], rv = r[k];
      acc += wv.x * rv.x + wv.y * rv.y + wv.z * rv.z + wv.w * rv.w;
    }
    ob[e] = acc;
  }
}

// ---------------------------------------------------------------------------
// Kernel 4: out[b,t,e] = sum_s attn[b,t,s] * ss_o[b,s,e]
// ss_o[b] (32 KB) + attn chunk in LDS; thread owns float2 of e; coalesced
// float2 stores.
// ---------------------------------------------------------------------------
#define K4_TOK 64
__global__ __launch_bounds__(256) void out_k(const float* __restrict__ attn,
                                             const float* __restrict__ ss_o,
                                             float* __restrict__ out) {
  __shared__ __align__(16) float ss[S_ * D_];       // 32 KB
  __shared__ __align__(16) float a_s[K4_TOK * S_];  // 4 KB
  const int chunks = T_ / K4_TOK;
  const int b = blockIdx.x / chunks;
  const int t0 = (blockIdx.x % chunks) * K4_TOK;

  const float* sb = ss_o + (size_t)b * S_ * D_;
  for (int i = threadIdx.x; i < S_ * D_; i += 256) ss[i] = sb[i];
  const float* ab = attn + ((size_t)b * T_ + t0) * S_;
  for (int i = threadIdx.x; i < K4_TOK * S_; i += 256) a_s[i] = ab[i];
  __syncthreads();

  const int e0 = threadIdx.x << 1;
  float* ob = out + ((size_t)b * T_ + t0) * D_;
  for (int t = 0; t < K4_TOK; ++t) {
    const float4* ap = (const float4*)(a_s + t * S_);  // broadcast
    float4 a0 = ap[0], a1 = ap[1], a2 = ap[2], a3 = ap[3];
    float av[S_] = {a0.x, a0.y, a0.z, a0.w, a1.x, a1.y, a1.z, a1.w,
                    a2.x, a2.y, a2.z, a2.w, a3.x, a3.y, a3.z, a3.w};
    float2 acc = make_float2(0.f, 0.f);
#pragma unroll
    for (int s = 0; s < S_; ++s) {
      float2 sv = *(const float2*)(ss + s * D_ + e0);
      acc.x += av[s] * sv.x;
      acc.y += av[s] * sv.y;
    }
    float2* op = (float2*)(ob + (size_t)t * D_);
    op[threadIdx.x] = acc;
  }
}

// ---------------------------------------------------------------------------
extern "C" void kernel_launch(void* const* d_in, const int* in_sizes, int n_in,
                              void* d_out, int out_size, void* d_ws, size_t ws_size,
                              hipStream_t stream) {
  const float* x          = (const float*)d_in[0];  // [B,T,D]
  const float* centers    = (const float*)d_in[1];  // [S,D]
  const float* log_scales = (const float*)d_in[2];  // [S]
  const float* Wv         = (const float*)d_in[3];  // [D,D]
  const float* Wo         = (const float*)d_in[4];  // [D,D]
  float* out = (float*)d_out;                       // [B,T,D]

  // workspace layout
  float* attn = (float*)d_ws;                         // B*T*S   = 2 MB
  float* ts   = attn + (size_t)B_ * T_ * S_;          // B*S*D   = 128 KB
  float* ss_o = ts + (size_t)B_ * S_ * D_;            // B*S*D   = 128 KB

  // zero the atomic-accumulation target (ws is poisoned 0xAA before each call)
  hipMemsetAsync(ts, 0, (size_t)B_ * S_ * D_ * sizeof(float), stream);

  attn_k<<<2048, 256, 0, stream>>>(x, centers, log_scales, attn);
  ts_k<<<B_ * (T_ / K2_TOK), 512, 0, stream>>>(x, attn, ts);
  ssgemm_k<<<B_ * S_, 256, 0, stream>>>(ts, Wv, Wo, ss_o);
  out_k<<<B_ * (T_ / K4_TOK), 256, 0, stream>>>(attn, ss_o, out);
}

// Round 2
// 202.724 us; speedup vs baseline: 1.3038x; 1.3038x over previous
//
#include <hip/hip_runtime.h>
#include <hip/hip_bf16.h>
#include <math.h>

// Problem constants (from reference): B=4, T=8192, D=512, S=16
#define B_ 4
#define T_ 8192
#define D_ 512
#define S_ 16

// ---------------------------------------------------------------------------
// Reduce-scatter across a wave: input vals[16] per lane (partial sums),
// output: full 64-lane sum of splat s=(lane>>2)&15, returned in every lane.
// Recursive halving: 15 shuffles + 2 finishing shuffles (vs 102 for full
// 17-value butterfly).
// ---------------------------------------------------------------------------
__device__ __forceinline__ float reduce_scatter16(float vals[S_], int lane) {
  {
    const int bit = (lane >> 5) & 1;
#pragma unroll
    for (int i = 0; i < 8; ++i) {
      float send = bit ? vals[i] : vals[i + 8];
      float keep = bit ? vals[i + 8] : vals[i];
      vals[i] = keep + __shfl_xor(send, 32, 64);
    }
  }
  {
    const int bit = (lane >> 4) & 1;
#pragma unroll
    for (int i = 0; i < 4; ++i) {
      float send = bit ? vals[i] : vals[i + 4];
      float keep = bit ? vals[i + 4] : vals[i];
      vals[i] = keep + __shfl_xor(send, 16, 64);
    }
  }
  {
    const int bit = (lane >> 3) & 1;
#pragma unroll
    for (int i = 0; i < 2; ++i) {
      float send = bit ? vals[i] : vals[i + 2];
      float keep = bit ? vals[i + 2] : vals[i];
      vals[i] = keep + __shfl_xor(send, 8, 64);
    }
  }
  {
    const int bit = (lane >> 2) & 1;
    float send = bit ? vals[0] : vals[1];
    float keep = bit ? vals[1] : vals[0];
    float v = keep + __shfl_xor(send, 4, 64);
    v += __shfl_xor(v, 2, 64);
    v += __shfl_xor(v, 1, 64);
    return v;
  }
}

__device__ __forceinline__ float dot4(float4 a, float4 b) {
  return a.x * b.x + a.y * b.y + a.z * b.z + a.w * b.w;
}

// ---------------------------------------------------------------------------
// Kernel 1: attn[t,s] = softmax_s( -0.5*||x[t]-c[s]||^2 / scale[s]^2 )
// One wave per token. Lane holds x elements [4*lane+256*j], j=0,1 (float4s).
// Centers in registers (128 VGPRs). Reduce-scatter puts logit for
// s=(lane>>2)&15 in each lane; softmax shuffles over lane bits 2..5.
// ---------------------------------------------------------------------------
__global__ __launch_bounds__(256) void attn_k(const float* __restrict__ x,
                                              const float* __restrict__ centers,
                                              const float* __restrict__ log_scales,
                                              float* __restrict__ attn) {
  const int lane = threadIdx.x & 63;
  const int wid = (blockIdx.x << 2) + (threadIdx.x >> 6);
  const int nw = gridDim.x << 2;
  const int myS = (lane >> 2) & 15;

  // centers in registers
  float4 c_reg[S_][2];
#pragma unroll
  for (int s = 0; s < S_; ++s)
#pragma unroll
    for (int j = 0; j < 2; ++j)
      c_reg[s][j] = *(const float4*)(centers + s * D_ + (j << 8) + (lane << 2));

  // c2 for myS via the same reduce-scatter
  float c2;
  {
    float vals[S_];
#pragma unroll
    for (int s = 0; s < S_; ++s)
      vals[s] = dot4(c_reg[s][0], c_reg[s][0]) + dot4(c_reg[s][1], c_reg[s][1]);
    c2 = reduce_scatter16(vals, lane);
  }
  const float sc = fminf(fmaxf(__expf(log_scales[myS]), 0.1f), 2.0f);
  const float inv2 = 0.5f / (sc * sc);

  const int total = B_ * T_;
  for (int t = wid; t < total; t += nw) {
    const float* xr = x + (size_t)t * D_;
    float4 xv0 = *(const float4*)(xr + (lane << 2));
    float4 xv1 = *(const float4*)(xr + 256 + (lane << 2));
    float x2p = dot4(xv0, xv0) + dot4(xv1, xv1);

    float vals[S_];
#pragma unroll
    for (int s = 0; s < S_; ++s)
      vals[s] = x2p - 2.f * (dot4(xv0, c_reg[s][0]) + dot4(xv1, c_reg[s][1]));

    float v = reduce_scatter16(vals, lane);  // = x2 - 2*dot(x,c_myS)
    float logit = -(v + c2) * inv2;

    // softmax over the 16 splats (lane bits 2..5)
    float m = logit;
    m = fmaxf(m, __shfl_xor(m, 4, 64));
    m = fmaxf(m, __shfl_xor(m, 8, 64));
    m = fmaxf(m, __shfl_xor(m, 16, 64));
    m = fmaxf(m, __shfl_xor(m, 32, 64));
    float e = __expf(logit - m);
    float ssum = e;
    ssum += __shfl_xor(ssum, 4, 64);
    ssum += __shfl_xor(ssum, 8, 64);
    ssum += __shfl_xor(ssum, 16, 64);
    ssum += __shfl_xor(ssum, 32, 64);
    if ((lane & 3) == 0) attn[(size_t)t * S_ + myS] = e / ssum;
  }
}

// ---------------------------------------------------------------------------
// Kernel 2: ts[b,s,d] = sum_t attn[b,t,s] * x[b,t,d]
// Thread-per-d-column; attn values are wave-uniform loads (scalar path);
// no LDS. Split over token chunks, fp32 atomics for the reduction.
// ---------------------------------------------------------------------------
#define K2_TOK 128
__global__ __launch_bounds__(512) void ts_k(const float* __restrict__ x,
                                            const float* __restrict__ attn,
                                            float* __restrict__ ts) {
  const int chunks = T_ / K2_TOK;  // 64
  const int b = blockIdx.x / chunks;
  const int t0 = (blockIdx.x % chunks) * K2_TOK;
  const int d = threadIdx.x;

  float acc[S_];
#pragma unroll
  for (int s = 0; s < S_; ++s) acc[s] = 0.f;

  const float* xb = x + ((size_t)b * T_ + t0) * D_ + d;
  const float4* ab = (const float4*)(attn + ((size_t)b * T_ + t0) * S_);

#pragma unroll 4
  for (int t = 0; t < K2_TOK; ++t) {
    float xv = xb[(size_t)t * D_];
    float4 a0 = ab[t * 4 + 0], a1 = ab[t * 4 + 1];
    float4 a2 = ab[t * 4 + 2], a3 = ab[t * 4 + 3];
    acc[0]  += a0.x * xv; acc[1]  += a0.y * xv; acc[2]  += a0.z * xv; acc[3]  += a0.w * xv;
    acc[4]  += a1.x * xv; acc[5]  += a1.y * xv; acc[6]  += a1.z * xv; acc[7]  += a1.w * xv;
    acc[8]  += a2.x * xv; acc[9]  += a2.y * xv; acc[10] += a2.z * xv; acc[11] += a2.w * xv;
    acc[12] += a3.x * xv; acc[13] += a3.y * xv; acc[14] += a3.z * xv; acc[15] += a3.w * xv;
  }

  float* tb = ts + (size_t)b * S_ * D_ + d;
#pragma unroll
  for (int s = 0; s < S_; ++s) atomicAdd(tb + s * D_, acc[s]);
}

// ---------------------------------------------------------------------------
// Kernel 3 (x2): out[r,e] = sum_k in[r,k] * W[e,k]   (r = 0..63 = b*S+s)
// Split-K=4 + atomicAdd into pre-zeroed out. 512 blocks -> enough waves to
// hide latency (the old ssgemm_k had 64 blocks, 2.8% occupancy, 76 us).
// ---------------------------------------------------------------------------
__global__ __launch_bounds__(256) void proj_k(const float* __restrict__ in,
                                              const float* __restrict__ W,
                                              float* __restrict__ out) {
  const int gid = blockIdx.x * 256 + threadIdx.x;
  const int e = gid & 511;
  const int rk = gid >> 9;  // 0..255
  const int r = rk >> 2;    // 0..63
  const int kc = rk & 3;    // 0..3
  const float4* w4 = (const float4*)(W + (size_t)e * D_ + kc * 128);
  const float4* i4 = (const float4*)(in + (size_t)r * D_ + kc * 128);
  float acc = 0.f;
#pragma unroll
  for (int k = 0; k < 32; ++k) acc += dot4(w4[k], i4[k]);
  atomicAdd(out + (size_t)r * D_ + e, acc);
}

// ---------------------------------------------------------------------------
// Kernel 4: out[b,t,e] = sum_s attn[b,t,s] * ss_o[b,s,e]
// ss_o slice lives in registers (16 x float2 per lane); attn wave-uniform
// loads; coalesced float2 stores. No LDS.
// ---------------------------------------------------------------------------
#define K4_TOK 128
__global__ __launch_bounds__(256) void out_k(const float* __restrict__ attn,
                                             const float* __restrict__ ss_o,
                                             float* __restrict__ out) {
  const int chunks = T_ / K4_TOK;  // 64
  const int b = blockIdx.x / chunks;
  const int t0 = (blockIdx.x % chunks) * K4_TOK;
  const int w = threadIdx.x >> 6;
  const int lane = threadIdx.x & 63;
  const int e0 = (w << 7) + (lane << 1);

  float2 ssf[S_];
  const float* sb = ss_o + (size_t)b * S_ * D_;
#pragma unroll
  for (int s = 0; s < S_; ++s) ssf[s] = *(const float2*)(sb + s * D_ + e0);

  const float4* ab = (const float4*)(attn + ((size_t)b * T_ + t0) * S_);
  float* ob = out + ((size_t)b * T_ + t0) * D_ + e0;

#pragma unroll 2
  for (int t = 0; t < K4_TOK; ++t) {
    float4 a0 = ab[t * 4 + 0], a1 = ab[t * 4 + 1];
    float4 a2 = ab[t * 4 + 2], a3 = ab[t * 4 + 3];
    float av[S_] = {a0.x, a0.y, a0.z, a0.w, a1.x, a1.y, a1.z, a1.w,
                    a2.x, a2.y, a2.z, a2.w, a3.x, a3.y, a3.z, a3.w};
    float2 acc = make_float2(0.f, 0.f);
#pragma unroll
    for (int s = 0; s < S_; ++s) {
      acc.x += av[s] * ssf[s].x;
      acc.y += av[s] * ssf[s].y;
    }
    *(float2*)(ob + (size_t)t * D_) = acc;
  }
}

// ---------------------------------------------------------------------------
extern "C" void kernel_launch(void* const* d_in, const int* in_sizes, int n_in,
                              void* d_out, int out_size, void* d_ws, size_t ws_size,
                              hipStream_t stream) {
  const float* x          = (const float*)d_in[0];  // [B,T,D]
  const float* centers    = (const float*)d_in[1];  // [S,D]
  const float* log_scales = (const float*)d_in[2];  // [S]
  const float* Wv         = (const float*)d_in[3];  // [D,D]
  const float* Wo         = (const float*)d_in[4];  // [D,D]
  float* out = (float*)d_out;                       // [B,T,D]

  // workspace layout (floats): attn | ts | tmp | ss_o
  float* attn = (float*)d_ws;                        // B*T*S   = 2 MB
  float* ts   = attn + (size_t)B_ * T_ * S_;         // B*S*D   = 128 KB
  float* tmp  = ts + (size_t)B_ * S_ * D_;           // B*S*D   = 128 KB
  float* ss_o = tmp + (size_t)B_ * S_ * D_;          // B*S*D   = 128 KB

  // zero the three atomic-accumulation targets in one memset
  hipMemsetAsync(ts, 0, (size_t)3 * B_ * S_ * D_ * sizeof(float), stream);

  attn_k<<<2048, 256, 0, stream>>>(x, centers, log_scales, attn);
  ts_k<<<B_ * (T_ / K2_TOK), 512, 0, stream>>>(x, attn, ts);
  proj_k<<<512, 256, 0, stream>>>(ts, Wv, tmp);    // tmp = ts @ Wv^T
  proj_k<<<512, 256, 0, stream>>>(tmp, Wo, ss_o);  // ss_o = tmp @ Wo^T
  out_k<<<B_ * (T_ / K4_TOK), 256, 0, stream>>>(attn, ss_o, out);
}

// Round 3
// 193.963 us; speedup vs baseline: 1.3626x; 1.0452x over previous
//
#include <hip/hip_runtime.h>
#include <hip/hip_bf16.h>
#include <math.h>

// Problem constants (from reference): B=4, T=8192, D=512, S=16
#define B_ 4
#define T_ 8192
#define D_ 512
#define S_ 16

// ---------------------------------------------------------------------------
// Reduce-scatter across a wave: input vals[16] per lane (partial sums),
// output: full 64-lane sum of splat s=(lane>>2)&15, returned in every lane.
// ---------------------------------------------------------------------------
__device__ __forceinline__ float reduce_scatter16(float vals[S_], int lane) {
  {
    const int bit = (lane >> 5) & 1;
#pragma unroll
    for (int i = 0; i < 8; ++i) {
      float send = bit ? vals[i] : vals[i + 8];
      float keep = bit ? vals[i + 8] : vals[i];
      vals[i] = keep + __shfl_xor(send, 32, 64);
    }
  }
  {
    const int bit = (lane >> 4) & 1;
#pragma unroll
    for (int i = 0; i < 4; ++i) {
      float send = bit ? vals[i] : vals[i + 4];
      float keep = bit ? vals[i + 4] : vals[i];
      vals[i] = keep + __shfl_xor(send, 16, 64);
    }
  }
  {
    const int bit = (lane >> 3) & 1;
#pragma unroll
    for (int i = 0; i < 2; ++i) {
      float send = bit ? vals[i] : vals[i + 2];
      float keep = bit ? vals[i + 2] : vals[i];
      vals[i] = keep + __shfl_xor(send, 8, 64);
    }
  }
  {
    const int bit = (lane >> 2) & 1;
    float send = bit ? vals[0] : vals[1];
    float keep = bit ? vals[1] : vals[0];
    float v = keep + __shfl_xor(send, 4, 64);
    v += __shfl_xor(v, 2, 64);
    v += __shfl_xor(v, 1, 64);
    return v;
  }
}

__device__ __forceinline__ float dot4(float4 a, float4 b) {
  return a.x * b.x + a.y * b.y + a.z * b.z + a.w * b.w;
}

// ---------------------------------------------------------------------------
// Kernel 1: attn[t,s] = softmax_s( -0.5*||x[t]-c[s]||^2 / scale[s]^2 )
// One wave per TOKEN PAIR (2 independent reduce chains in flight to hide
// shuffle latency + double the loads outstanding). Centers in registers.
// Blocks 0..63 also zero the 128 KB ts accumulator (replaces a memset
// dispatch; stream order guarantees completion before ts_k's atomics).
// ---------------------------------------------------------------------------
__global__ __launch_bounds__(256, 2) void attn_k(const float* __restrict__ x,
                                                 const float* __restrict__ centers,
                                                 const float* __restrict__ log_scales,
                                                 float* __restrict__ attn,
                                                 float* __restrict__ ts) {
  // zero ts[B*S*D] = 32768 floats: 64 blocks x 256 threads x float2
  if (blockIdx.x < 64) {
    *(float2*)(ts + blockIdx.x * 512 + threadIdx.x * 2) = make_float2(0.f, 0.f);
  }

  const int lane = threadIdx.x & 63;
  const int wid = (blockIdx.x << 2) + (threadIdx.x >> 6);
  const int nw = gridDim.x << 2;
  const int myS = (lane >> 2) & 15;

  // centers in registers (128 VGPRs)
  float4 c_reg[S_][2];
#pragma unroll
  for (int s = 0; s < S_; ++s)
#pragma unroll
    for (int j = 0; j < 2; ++j)
      c_reg[s][j] = *(const float4*)(centers + s * D_ + (j << 8) + (lane << 2));

  float c2;
  {
    float vals[S_];
#pragma unroll
    for (int s = 0; s < S_; ++s)
      vals[s] = dot4(c_reg[s][0], c_reg[s][0]) + dot4(c_reg[s][1], c_reg[s][1]);
    c2 = reduce_scatter16(vals, lane);
  }
  const float sc = fminf(fmaxf(__expf(log_scales[myS]), 0.1f), 2.0f);
  const float inv2 = 0.5f / (sc * sc);

  const int npairs = (B_ * T_) / 2;
  for (int tp = wid; tp < npairs; tp += nw) {
    const int t0 = tp << 1;
    const float* xr = x + (size_t)t0 * D_;
    // token 0 and token 1 loads issued together (4 KB/wave in flight)
    float4 a0 = *(const float4*)(xr + (lane << 2));
    float4 a1 = *(const float4*)(xr + 256 + (lane << 2));
    float4 b0 = *(const float4*)(xr + 512 + (lane << 2));
    float4 b1 = *(const float4*)(xr + 768 + (lane << 2));

    float x2a = dot4(a0, a0) + dot4(a1, a1);
    float x2b = dot4(b0, b0) + dot4(b1, b1);

    float va[S_], vb[S_];
#pragma unroll
    for (int s = 0; s < S_; ++s) {
      va[s] = x2a - 2.f * (dot4(a0, c_reg[s][0]) + dot4(a1, c_reg[s][1]));
      vb[s] = x2b - 2.f * (dot4(b0, c_reg[s][0]) + dot4(b1, c_reg[s][1]));
    }

    float ra = reduce_scatter16(va, lane);
    float rb = reduce_scatter16(vb, lane);
    float la = -(ra + c2) * inv2;
    float lb = -(rb + c2) * inv2;

    // softmax over splats (lane bits 2..5); two independent chains interleave
    float ma = la, mb = lb;
    ma = fmaxf(ma, __shfl_xor(ma, 4, 64));  mb = fmaxf(mb, __shfl_xor(mb, 4, 64));
    ma = fmaxf(ma, __shfl_xor(ma, 8, 64));  mb = fmaxf(mb, __shfl_xor(mb, 8, 64));
    ma = fmaxf(ma, __shfl_xor(ma, 16, 64)); mb = fmaxf(mb, __shfl_xor(mb, 16, 64));
    ma = fmaxf(ma, __shfl_xor(ma, 32, 64)); mb = fmaxf(mb, __shfl_xor(mb, 32, 64));
    float ea = __expf(la - ma), eb = __expf(lb - mb);
    float sa = ea, sb = eb;
    sa += __shfl_xor(sa, 4, 64);  sb += __shfl_xor(sb, 4, 64);
    sa += __shfl_xor(sa, 8, 64);  sb += __shfl_xor(sb, 8, 64);
    sa += __shfl_xor(sa, 16, 64); sb += __shfl_xor(sb, 16, 64);
    sa += __shfl_xor(sa, 32, 64); sb += __shfl_xor(sb, 32, 64);
    if ((lane & 3) == 0) {
      attn[(size_t)t0 * S_ + myS] = ea / sa;
      attn[(size_t)(t0 + 1) * S_ + myS] = eb / sb;
    }
  }
}

// ---------------------------------------------------------------------------
// Kernel 2: ts[b,s,d] = sum_t attn[b,t,s] * x[b,t,d]
// Thread-per-d-column; attn loads are wave-uniform. Unroll 16 -> ~32 KB of
// x-loads in flight per CU (8 waves x 16 x 256 B) to cover ~900-cyc HBM
// latency at 1 block/CU occupancy.
// ---------------------------------------------------------------------------
#define K2_TOK 128
__global__ __launch_bounds__(512) void ts_k(const float* __restrict__ x,
                                            const float* __restrict__ attn,
                                            float* __restrict__ ts) {
  const int chunks = T_ / K2_TOK;  // 64
  const int b = blockIdx.x / chunks;
  const int t0 = (blockIdx.x % chunks) * K2_TOK;
  const int d = threadIdx.x;

  float acc[S_];
#pragma unroll
  for (int s = 0; s < S_; ++s) acc[s] = 0.f;

  const float* xb = x + ((size_t)b * T_ + t0) * D_ + d;
  const float4* ab = (const float4*)(attn + ((size_t)b * T_ + t0) * S_);

#pragma unroll 16
  for (int t = 0; t < K2_TOK; ++t) {
    float xv = xb[(size_t)t * D_];
    float4 a0 = ab[t * 4 + 0], a1 = ab[t * 4 + 1];
    float4 a2 = ab[t * 4 + 2], a3 = ab[t * 4 + 3];
    acc[0]  += a0.x * xv; acc[1]  += a0.y * xv; acc[2]  += a0.z * xv; acc[3]  += a0.w * xv;
    acc[4]  += a1.x * xv; acc[5]  += a1.y * xv; acc[6]  += a1.z * xv; acc[7]  += a1.w * xv;
    acc[8]  += a2.x * xv; acc[9]  += a2.y * xv; acc[10] += a2.z * xv; acc[11] += a2.w * xv;
    acc[12] += a3.x * xv; acc[13] += a3.y * xv; acc[14] += a3.z * xv; acc[15] += a3.w * xv;
  }

  float* tb = ts + (size_t)b * S_ * D_ + d;
#pragma unroll
  for (int s = 0; s < S_; ++s) atomicAdd(tb + s * D_, acc[s]);
}

// ---------------------------------------------------------------------------
// Kernel 3 (x2): out[r,e] = sum_k in[r,k] * W[e,k]   (r = 0..63 = b*S+s)
// Split-K=4 reduced in LDS (deterministic, no atomics, no pre-zeroing).
// Grid 512 blocks x 256 threads: (r:64) x (e-block:8); thread = (kc:4, el:64).
// ---------------------------------------------------------------------------
__global__ __launch_bounds__(256) void proj_k(const float* __restrict__ in,
                                              const float* __restrict__ W,
                                              float* __restrict__ out) {
  __shared__ float red[4][64];
  const int r = blockIdx.x >> 3;
  const int eb = blockIdx.x & 7;
  const int el = threadIdx.x & 63;
  const int kc = threadIdx.x >> 6;
  const int e = (eb << 6) + el;

  const float4* w4 = (const float4*)(W + (size_t)e * D_ + kc * 128);
  const float4* i4 = (const float4*)(in + (size_t)r * D_ + kc * 128);
  float acc = 0.f;
#pragma unroll
  for (int k = 0; k < 32; ++k) acc += dot4(w4[k], i4[k]);

  red[kc][el] = acc;
  __syncthreads();
  if (kc == 0)
    out[(size_t)r * D_ + e] = red[0][el] + red[1][el] + red[2][el] + red[3][el];
}

// ---------------------------------------------------------------------------
// Kernel 4: out[b,t,e] = sum_s attn[b,t,s] * ss_o[b,s,e]
// ss_o slice in registers (16 x float2); attn wave-uniform loads; coalesced
// float2 stores. 512 blocks for occupancy; unroll 4.
// ---------------------------------------------------------------------------
#define K4_TOK 64
__global__ __launch_bounds__(256) void out_k(const float* __restrict__ attn,
                                             const float* __restrict__ ss_o,
                                             float* __restrict__ out) {
  const int chunks = T_ / K4_TOK;  // 128
  const int b = blockIdx.x / chunks;
  const int t0 = (blockIdx.x % chunks) * K4_TOK;
  const int w = threadIdx.x >> 6;
  const int lane = threadIdx.x & 63;
  const int e0 = (w << 7) + (lane << 1);

  float2 ssf[S_];
  const float* sb = ss_o + (size_t)b * S_ * D_;
#pragma unroll
  for (int s = 0; s < S_; ++s) ssf[s] = *(const float2*)(sb + s * D_ + e0);

  const float4* ab = (const float4*)(attn + ((size_t)b * T_ + t0) * S_);
  float* ob = out + ((size_t)b * T_ + t0) * D_ + e0;

#pragma unroll 4
  for (int t = 0; t < K4_TOK; ++t) {
    float4 a0 = ab[t * 4 + 0], a1 = ab[t * 4 + 1];
    float4 a2 = ab[t * 4 + 2], a3 = ab[t * 4 + 3];
    float av[S_] = {a0.x, a0.y, a0.z, a0.w, a1.x, a1.y, a1.z, a1.w,
                    a2.x, a2.y, a2.z, a2.w, a3.x, a3.y, a3.z, a3.w};
    float2 acc = make_float2(0.f, 0.f);
#pragma unroll
    for (int s = 0; s < S_; ++s) {
      acc.x += av[s] * ssf[s].x;
      acc.y += av[s] * ssf[s].y;
    }
    *(float2*)(ob + (size_t)t * D_) = acc;
  }
}

// ---------------------------------------------------------------------------
extern "C" void kernel_launch(void* const* d_in, const int* in_sizes, int n_in,
                              void* d_out, int out_size, void* d_ws, size_t ws_size,
                              hipStream_t stream) {
  const float* x          = (const float*)d_in[0];  // [B,T,D]
  const float* centers    = (const float*)d_in[1];  // [S,D]
  const float* log_scales = (const float*)d_in[2];  // [S]
  const float* Wv         = (const float*)d_in[3];  // [D,D]
  const float* Wo         = (const float*)d_in[4];  // [D,D]
  float* out = (float*)d_out;                       // [B,T,D]

  // workspace layout (floats): attn | ts | tmp | ss_o
  float* attn = (float*)d_ws;                        // B*T*S   = 2 MB
  float* ts   = attn + (size_t)B_ * T_ * S_;         // B*S*D   = 128 KB
  float* tmp  = ts + (size_t)B_ * S_ * D_;           // B*S*D   = 128 KB
  float* ss_o = tmp + (size_t)B_ * S_ * D_;          // B*S*D   = 128 KB

  // 5 dispatches, no memset: attn_k zeroes ts (stream-ordered before ts_k).
  attn_k<<<2048, 256, 0, stream>>>(x, centers, log_scales, attn, ts);
  ts_k<<<B_ * (T_ / K2_TOK), 512, 0, stream>>>(x, attn, ts);
  proj_k<<<512, 256, 0, stream>>>(ts, Wv, tmp);    // tmp = ts @ Wv^T
  proj_k<<<512, 256, 0, stream>>>(tmp, Wo, ss_o);  // ss_o = tmp @ Wo^T
  out_k<<<B_ * (T_ / K4_TOK), 256, 0, stream>>>(attn, ss_o, out);
}